// Round 5
// baseline (572.546 us; speedup 1.0000x reference)
//
#include <hip/hip_runtime.h>

typedef __attribute__((ext_vector_type(8))) short short8;
typedef __attribute__((ext_vector_type(4))) float f32x4;

#define S_LEN 2048
#define DH 64

__device__ __forceinline__ unsigned short f2bf(float x) {
  unsigned u = __builtin_bit_cast(unsigned, x);
  u += 0x7fffu + ((u >> 16) & 1u);
  return (unsigned short)(u >> 16);
}

// ---- detect whether mask was passed as uint8 (stride 1) or int32 (stride 4)
__global__ void detect_stride_k(const unsigned char* __restrict__ m, int* flag) {
  __shared__ int any;
  if (threadIdx.x == 0) any = 0;
  __syncthreads();
  int acc = 0;
  for (int i = threadIdx.x; i < 4096; i += 256)
    if (i & 3) acc |= m[i];
  if (acc) atomicOr(&any, 1);
  __syncthreads();
  if (threadIdx.x == 0) *flag = any ? 1 : 4;
}

// ---- K: f32 -> bf16, row-major [bh][t][d]
__global__ void conv_k_kernel(const float* __restrict__ k, char* __restrict__ kbf) {
  int idx = blockIdx.x * 256 + threadIdx.x;  // 524288 threads, 8 elems each
  const float4* s = (const float4*)k + (size_t)idx * 2;
  float4 a = s[0], b = s[1];
  int4 o;
  o.x = (int)f2bf(a.x) | ((int)f2bf(a.y) << 16);
  o.y = (int)f2bf(a.z) | ((int)f2bf(a.w) << 16);
  o.z = (int)f2bf(b.x) | ((int)f2bf(b.y) << 16);
  o.w = (int)f2bf(b.z) | ((int)f2bf(b.w) << 16);
  ((int4*)kbf)[idx] = o;
}

// ---- V: f32 [bh][t][d] -> bf16 transposed [bh][d][t]
__global__ void trans_v_kernel(const float* __restrict__ v, char* __restrict__ vtbf) {
  int gt = blockIdx.x * 256 + threadIdx.x;
  int wid = gt >> 6;            // 16384 wave-jobs
  int lane = gt & 63;
  int bh = wid >> 9;
  int rem = wid & 511;
  int d0 = (rem >> 5) * 4;      // 0,4,...,60
  int t = (rem & 31) * 64 + lane;
  float4 val = *(const float4*)(v + ((size_t)bh * S_LEN + t) * DH + d0);
  unsigned short* o = (unsigned short*)vtbf;
  size_t base = ((size_t)bh * DH + d0) * S_LEN + t;
  o[base]             = f2bf(val.x);
  o[base + S_LEN]     = f2bf(val.y);
  o[base + 2 * S_LEN] = f2bf(val.z);
  o[base + 3 * S_LEN] = f2bf(val.w);
}

// ======= FUSED, barrier-free: each wave owns 16 q-rows end-to-end ==========
// 1024 blocks x 4 waves = 4096 waves = 16 waves/CU (2x R4's TLP)
__global__ __launch_bounds__(256, 4)
void attn_fused(const float* __restrict__ qsrc,
                const unsigned char* __restrict__ maskb,
                const char* __restrict__ kbf,
                const char* __restrict__ vtbf,
                const int* __restrict__ flagp,
                float* __restrict__ out) {
  // per-wave P bounce: [16 q rows][144 B] (stride 144 -> 2-way max bank alias)
  __shared__ __align__(16) char pbuf[4][2304];

  const int tid = threadIdx.x;
  const int lane = tid & 63;
  const int w = tid >> 6;
  const int l15 = lane & 15;
  const int g = lane >> 4;

  // XCD-aware swizzle: 1024 blocks -> 4 consecutive bh per XCD
  int raw = blockIdx.x;
  int swz = (raw & 7) * 128 + (raw >> 3);
  const int bh = swz >> 5;
  const int qblk = swz & 31;
  const int b = bh >> 4;
  const int q0 = qblk * 64 + w * 16;   // this wave's 16 q-rows

  const int stride = *flagp;
  const unsigned char* mb = maskb + (size_t)b * S_LEN * S_LEN * (size_t)stride;

  // Q fragments: lane holds Q[q0+l15][32kc+8g+j]
  short8 qf[2];
#pragma unroll
  for (int kc = 0; kc < 2; ++kc) {
    const float* qp = qsrc + ((size_t)bh * S_LEN + q0 + l15) * DH + 32 * kc + 8 * g;
    float4 x = *(const float4*)qp;
    float4 y = *(const float4*)(qp + 4);
    short8 f;
    f[0] = (short)f2bf(x.x); f[1] = (short)f2bf(x.y);
    f[2] = (short)f2bf(x.z); f[3] = (short)f2bf(x.w);
    f[4] = (short)f2bf(y.x); f[5] = (short)f2bf(y.y);
    f[6] = (short)f2bf(y.z); f[7] = (short)f2bf(y.w);
    qf[kc] = f;
  }

  f32x4 acc[4];
#pragma unroll
  for (int i = 0; i < 4; ++i) acc[i] = (f32x4){0.f, 0.f, 0.f, 0.f};
  float lp = 0.f;

  const char* kb = kbf + (size_t)bh * (S_LEN * DH * 2);
  const char* vb = vtbf + (size_t)bh * (DH * S_LEN * 2);
  char* pb = pbuf[w];

  // ---------------- PASS A: 64-t chunks, no barriers ----------------
  for (int t0 = 0; t0 < S_LEN; t0 += 64) {
    // K fragment loads (L2-resident): rows t0+16tc+l15, both d-halves
    short8 kf0[4], kf1[4];
#pragma unroll
    for (int tc = 0; tc < 4; ++tc) {
      const char* kr = kb + (size_t)(t0 + 16 * tc + l15) * 128;
      kf0[tc] = *(const short8*)(kr + 16 * g);
      kf1[tc] = *(const short8*)(kr + 64 + 16 * g);
    }
    // V^T fragment loads: row d=16dr+l15, t-halves 32kc
    short8 av[4][2];
#pragma unroll
    for (int dr = 0; dr < 4; ++dr) {
      const char* vr = vb + (size_t)(16 * dr + l15) * (S_LEN * 2) + t0 * 2 + 16 * g;
      av[dr][0] = *(const short8*)(vr);
      av[dr][1] = *(const short8*)(vr + 64);
    }

    // GEMM1 (swapped): lane holds S[q=q0+l15][t=t0+16tc+4g+r]
    f32x4 sf[4];
    f32x4 z = (f32x4){0.f, 0.f, 0.f, 0.f};
#pragma unroll
    for (int tc = 0; tc < 4; ++tc) {
      f32x4 t00 = __builtin_amdgcn_mfma_f32_16x16x32_bf16(kf0[tc], qf[0], z, 0, 0, 0);
      sf[tc] = __builtin_amdgcn_mfma_f32_16x16x32_bf16(kf1[tc], qf[1], t00, 0, 0, 0);
    }

    // mask + scale + exp-sum + pack into per-wave LDS chunk
    {
      const int q = q0 + l15;
      char* pbr = pb + l15 * 144;
#pragma unroll
      for (int tc = 0; tc < 4; ++tc) {
        const int t = t0 + 16 * tc + 4 * g;
        size_t eidx = (size_t)q * S_LEN + t;
        int m0, m1, m2, m3;
        if (stride == 1) {
          unsigned mv = *(const unsigned*)(mb + eidx);
          m0 = mv & 0xff; m1 = (mv >> 8) & 0xff; m2 = (mv >> 16) & 0xff; m3 = (mv >> 24) & 0xff;
        } else {
          uint4 mv = *(const uint4*)(mb + eidx * 4);
          m0 = mv.x; m1 = mv.y; m2 = mv.z; m3 = mv.w;
        }
        float s0 = m0 ? -1e9f : sf[tc][0] * 0.125f;
        float s1 = m1 ? -1e9f : sf[tc][1] * 0.125f;
        float s2 = m2 ? -1e9f : sf[tc][2] * 0.125f;
        float s3 = m3 ? -1e9f : sf[tc][3] * 0.125f;
        lp += __expf(s0) + __expf(s1) + __expf(s2) + __expf(s3);
        int2 pk;
        pk.x = (int)f2bf(s0) | ((int)f2bf(s1) << 16);
        pk.y = (int)f2bf(s2) | ((int)f2bf(s3) << 16);
        *(int2*)(pbr + 32 * tc + 8 * g) = pk;
      }
    }

    // P fragments back (wave-private LDS; HW orders write->read via lgkmcnt)
    short8 p0 = *(const short8*)(pb + l15 * 144 + 16 * g);
    short8 p1 = *(const short8*)(pb + l15 * 144 + 64 + 16 * g);

    // GEMM2: acc^T[d][q] += V^T · P^T
#pragma unroll
    for (int dr = 0; dr < 4; ++dr) {
      acc[dr] = __builtin_amdgcn_mfma_f32_16x16x32_bf16(av[dr][0], p0, acc[dr], 0, 0, 0);
      acc[dr] = __builtin_amdgcn_mfma_f32_16x16x32_bf16(av[dr][1], p1, acc[dr], 0, 0, 0);
    }
  }

  // row sums (row q0+l15 lives on lanes {l15, +16, +32, +48})
  float l = lp;
  l += __shfl_xor(l, 16);
  l += __shfl_xor(l, 32);
  const float inv = 1.0f / l;

  // write results: acc^T C-layout -> out[bh][q][d], float4 along d
#pragma unroll
  for (int dr = 0; dr < 4; ++dr) {
    const int q = q0 + l15;
    float4 o;
    o.x = acc[dr][0]; o.y = acc[dr][1];
    o.z = acc[dr][2]; o.w = acc[dr][3];
    *(float4*)(out + ((size_t)bh * S_LEN + q) * DH + 16 * dr + 4 * g) = o;
  }

  // ---------------- PASS B: barrier-free attention stream ----------------
  float* att = out + (size_t)4194304 + (size_t)bh * S_LEN * S_LEN;
#pragma unroll 1
  for (int it = 0; it < 32; ++it) {
    const int tb = it * 64;
    short8 kf0[4], kf1[4];
#pragma unroll
    for (int tc = 0; tc < 4; ++tc) {
      const char* kr = kb + (size_t)(tb + 16 * tc + l15) * 128;
      kf0[tc] = *(const short8*)(kr + 16 * g);
      kf1[tc] = *(const short8*)(kr + 64 + 16 * g);
    }
    f32x4 z = (f32x4){0.f, 0.f, 0.f, 0.f};
#pragma unroll
    for (int tc = 0; tc < 4; ++tc) {
      f32x4 t0f = __builtin_amdgcn_mfma_f32_16x16x32_bf16(kf0[tc], qf[0], z, 0, 0, 0);
      f32x4 sff = __builtin_amdgcn_mfma_f32_16x16x32_bf16(kf1[tc], qf[1], t0f, 0, 0, 0);
      const int q = q0 + l15;
      const int t = tb + 16 * tc + 4 * g;
      size_t eidx = (size_t)q * S_LEN + t;
      int m0, m1, m2, m3;
      if (stride == 1) {
        unsigned mv = *(const unsigned*)(mb + eidx);
        m0 = mv & 0xff; m1 = (mv >> 8) & 0xff; m2 = (mv >> 16) & 0xff; m3 = (mv >> 24) & 0xff;
      } else {
        uint4 mv = *(const uint4*)(mb + eidx * 4);
        m0 = mv.x; m1 = mv.y; m2 = mv.z; m3 = mv.w;
      }
      float s0 = m0 ? -1e9f : sff[0] * 0.125f;
      float s1 = m1 ? -1e9f : sff[1] * 0.125f;
      float s2 = m2 ? -1e9f : sff[2] * 0.125f;
      float s3 = m3 ? -1e9f : sff[3] * 0.125f;
      float4 e;
      e.x = __expf(s0) * inv;
      e.y = __expf(s1) * inv;
      e.z = __expf(s2) * inv;
      e.w = __expf(s3) * inv;
      *(float4*)(att + eidx) = e;
    }
  }
}

extern "C" void kernel_launch(void* const* d_in, const int* in_sizes, int n_in,
                              void* d_out, int out_size, void* d_ws, size_t ws_size,
                              hipStream_t stream) {
  (void)in_sizes; (void)n_in; (void)out_size; (void)ws_size;
  const float* q = (const float*)d_in[0];
  const float* k = (const float*)d_in[1];
  const float* v = (const float*)d_in[2];
  const unsigned char* mask = (const unsigned char*)d_in[3];
  float* out = (float*)d_out;

  char* ws = (char*)d_ws;
  int* flag = (int*)ws;
  char* kbf = ws + 256;                           // 8 MiB bf16 K
  char* vtbf = ws + 256 + 8 * 1024 * 1024;        // 8 MiB bf16 V^T

  detect_stride_k<<<1, 256, 0, stream>>>(mask, flag);
  conv_k_kernel<<<2048, 256, 0, stream>>>(k, kbf);
  trans_v_kernel<<<4096, 256, 0, stream>>>(v, vtbf);
  attn_fused<<<1024, 256, 0, stream>>>(q, mask, kbf, vtbf, flag, out);
}

// Round 6
// 350.453 us; speedup vs baseline: 1.6337x; 1.6337x over previous
//
#include <hip/hip_runtime.h>

typedef __attribute__((ext_vector_type(8))) short short8;
typedef __attribute__((ext_vector_type(4))) float f32x4;

#define S_LEN 2048
#define DH 64

__device__ __forceinline__ unsigned short f2bf(float x) {
  unsigned u = __builtin_bit_cast(unsigned, x);
  u += 0x7fffu + ((u >> 16) & 1u);
  return (unsigned short)(u >> 16);
}

// ---- detect whether mask was passed as uint8 (stride 1) or int32 (stride 4)
__global__ void detect_stride_k(const unsigned char* __restrict__ m, int* flag) {
  __shared__ int any;
  if (threadIdx.x == 0) any = 0;
  __syncthreads();
  int acc = 0;
  for (int i = threadIdx.x; i < 4096; i += 256)
    if (i & 3) acc |= m[i];
  if (acc) atomicOr(&any, 1);
  __syncthreads();
  if (threadIdx.x == 0) *flag = any ? 1 : 4;
}

// ---- K: f32 -> bf16, row-major [bh][t][d]
__global__ void conv_k_kernel(const float* __restrict__ k, char* __restrict__ kbf) {
  int idx = blockIdx.x * 256 + threadIdx.x;  // 524288 threads, 8 elems each
  const float4* s = (const float4*)k + (size_t)idx * 2;
  float4 a = s[0], b = s[1];
  int4 o;
  o.x = (int)f2bf(a.x) | ((int)f2bf(a.y) << 16);
  o.y = (int)f2bf(a.z) | ((int)f2bf(a.w) << 16);
  o.z = (int)f2bf(b.x) | ((int)f2bf(b.y) << 16);
  o.w = (int)f2bf(b.z) | ((int)f2bf(b.w) << 16);
  ((int4*)kbf)[idx] = o;
}

// ---- V: f32 [bh][t][d] -> bf16 transposed [bh][d][t]
__global__ void trans_v_kernel(const float* __restrict__ v, char* __restrict__ vtbf) {
  int gt = blockIdx.x * 256 + threadIdx.x;
  int wid = gt >> 6;            // 16384 wave-jobs
  int lane = gt & 63;
  int bh = wid >> 9;
  int rem = wid & 511;
  int d0 = (rem >> 5) * 4;      // 0,4,...,60
  int t = (rem & 31) * 64 + lane;
  float4 val = *(const float4*)(v + ((size_t)bh * S_LEN + t) * DH + d0);
  unsigned short* o = (unsigned short*)vtbf;
  size_t base = ((size_t)bh * DH + d0) * S_LEN + t;
  o[base]             = f2bf(val.x);
  o[base + S_LEN]     = f2bf(val.y);
  o[base + 2 * S_LEN] = f2bf(val.z);
  o[base + 3 * S_LEN] = f2bf(val.w);
}

// ======= FUSED: R1 structure, 8 waves/block (16 q-rows each) ================
// 512 blocks x 8 waves = 4096 waves = 16 waves/CU, same staging traffic as R1
__global__ __launch_bounds__(512, 4)
void attn_fused(const float* __restrict__ qsrc,
                const unsigned char* __restrict__ maskb,
                const char* __restrict__ kbf,
                const char* __restrict__ vtbf,
                const int* __restrict__ flagp,
                float* __restrict__ out) {
  __shared__ __align__(16) char kbuf[16384];   // K tile [128 t][64 d] bf16, XOR-swizzled
  __shared__ __align__(16) char vbuf[16384];   // V^T tile [64 d][128 t] bf16, XOR-swizzled
  __shared__ __align__(16) char pbuf[16384];   // per-wave P half [16 q][64 t] bf16, swizzled

  const int tid = threadIdx.x;
  const int lane = tid & 63;
  const int w = tid >> 6;              // 0..7
  const int l15 = lane & 15;
  const int g = lane >> 4;
  const int sw = (l15 & 7) << 4;

  // XCD-aware swizzle: 512 blocks -> 4 consecutive bh per XCD
  int raw = blockIdx.x;
  int swz = (raw & 7) * 64 + (raw >> 3);
  const int bh = swz >> 4;
  const int qblk = swz & 15;
  const int b = bh >> 4;
  const int qbase = qblk * 128;        // block's 128 q-rows
  const int q0 = qbase + w * 16;       // this wave's 16 q-rows

  const int stride = *flagp;
  const unsigned char* mb = maskb + (size_t)b * S_LEN * S_LEN * (size_t)stride;

  // Q fragments (B operand of swapped QK^T): lane holds Q[q0+l15][32kc+8g+j]
  short8 qf[2];
#pragma unroll
  for (int kc = 0; kc < 2; ++kc) {
    const float* qp = qsrc + ((size_t)bh * S_LEN + q0 + l15) * DH + 32 * kc + 8 * g;
    float4 x = *(const float4*)qp;
    float4 y = *(const float4*)(qp + 4);
    short8 f;
    f[0] = (short)f2bf(x.x); f[1] = (short)f2bf(x.y);
    f[2] = (short)f2bf(x.z); f[3] = (short)f2bf(x.w);
    f[4] = (short)f2bf(y.x); f[5] = (short)f2bf(y.y);
    f[6] = (short)f2bf(y.z); f[7] = (short)f2bf(y.w);
    qf[kc] = f;
  }

  f32x4 acc[4];
#pragma unroll
  for (int i = 0; i < 4; ++i) acc[i] = (f32x4){0.f, 0.f, 0.f, 0.f};
  float lp = 0.f;

  const char* ksrc_bh = kbf + (size_t)bh * (S_LEN * DH * 2);
  const char* vsrc_bh = vtbf + (size_t)bh * (DH * S_LEN * 2);
  char* pb = pbuf + w * 2048;          // 16 rows x 128 B

  // ---------------- PASS A ----------------
  for (int t0 = 0; t0 < S_LEN; t0 += 128) {
    __syncthreads();
    {  // stage K tile: 1024 int4, 512 threads x 2
      const char* src = ksrc_bh + (size_t)t0 * 128;
#pragma unroll
      for (int it = 0; it < 2; ++it) {
        int idx = it * 512 + tid;
        int r = idx >> 3, c = idx & 7;
        int4 val = *(const int4*)(src + r * 128 + c * 16);
        *(int4*)(kbuf + r * 128 + ((c * 16) ^ ((r & 7) << 4))) = val;
      }
    }
    {  // stage V^T tile: 1024 int4
      const char* src = vsrc_bh + (size_t)t0 * 2;
#pragma unroll
      for (int it = 0; it < 2; ++it) {
        int idx = it * 512 + tid;
        int r = idx >> 4, c = idx & 15;
        int4 val = *(const int4*)(src + (size_t)r * (S_LEN * 2) + c * 16);
        *(int4*)(vbuf + r * 256 + ((c * 16) ^ ((r & 7) << 4))) = val;
      }
    }
    __syncthreads();

    // GEMM1 (swapped): lane holds S[q=q0+l15][t=t0+16tc+4g+r]
    f32x4 sf[8];
#pragma unroll
    for (int tc = 0; tc < 8; ++tc) {
      const char* rowp = kbuf + (16 * tc + l15) * 128;
      short8 a0 = *(const short8*)(rowp + ((16 * g) ^ sw));
      short8 a1 = *(const short8*)(rowp + ((64 + 16 * g) ^ sw));
      f32x4 z = (f32x4){0.f, 0.f, 0.f, 0.f};
      f32x4 t00 = __builtin_amdgcn_mfma_f32_16x16x32_bf16(a0, qf[0], z, 0, 0, 0);
      sf[tc] = __builtin_amdgcn_mfma_f32_16x16x32_bf16(a1, qf[1], t00, 0, 0, 0);
    }

    // two 64-t halves: pack P half -> GEMM2 half (wave-private pbuf, no barrier)
    const int q = q0 + l15;
#pragma unroll
    for (int h = 0; h < 2; ++h) {
      char* pbr = pb + l15 * 128;
#pragma unroll
      for (int tq = 0; tq < 4; ++tq) {
        const int tc = 4 * h + tq;
        const int t = t0 + 16 * tc + 4 * g;
        size_t eidx = (size_t)q * S_LEN + t;
        int m0, m1, m2, m3;
        if (stride == 1) {
          unsigned mv = *(const unsigned*)(mb + eidx);
          m0 = mv & 0xff; m1 = (mv >> 8) & 0xff; m2 = (mv >> 16) & 0xff; m3 = (mv >> 24) & 0xff;
        } else {
          uint4 mv = *(const uint4*)(mb + eidx * 4);
          m0 = mv.x; m1 = mv.y; m2 = mv.z; m3 = mv.w;
        }
        float s0 = m0 ? -1e9f : sf[tc][0] * 0.125f;
        float s1 = m1 ? -1e9f : sf[tc][1] * 0.125f;
        float s2 = m2 ? -1e9f : sf[tc][2] * 0.125f;
        float s3 = m3 ? -1e9f : sf[tc][3] * 0.125f;
        lp += __expf(s0) + __expf(s1) + __expf(s2) + __expf(s3);
        int2 pk;
        pk.x = (int)f2bf(s0) | ((int)f2bf(s1) << 16);
        pk.y = (int)f2bf(s2) | ((int)f2bf(s3) << 16);
        *(int2*)(pbr + ((32 * tq + 8 * g) ^ sw)) = pk;
      }
      // P fragments back (compiler inserts lgkmcnt wait)
      short8 p0 = *(const short8*)(pb + l15 * 128 + ((16 * g) ^ sw));
      short8 p1 = *(const short8*)(pb + l15 * 128 + ((64 + 16 * g) ^ sw));
#pragma unroll
      for (int dr = 0; dr < 4; ++dr) {
        const char* vr = vbuf + (16 * dr + l15) * 256;
        short8 v0 = *(const short8*)(vr + ((h * 128 + 16 * g) ^ sw));
        short8 v1 = *(const short8*)(vr + ((h * 128 + 64 + 16 * g) ^ sw));
        acc[dr] = __builtin_amdgcn_mfma_f32_16x16x32_bf16(v0, p0, acc[dr], 0, 0, 0);
        acc[dr] = __builtin_amdgcn_mfma_f32_16x16x32_bf16(v1, p1, acc[dr], 0, 0, 0);
      }
    }
  }

  // row sums (row q0+l15 lives on lanes {l15, +16, +32, +48})
  float l = lp;
  l += __shfl_xor(l, 16);
  l += __shfl_xor(l, 32);
  const float inv = 1.0f / l;

  // write results: acc^T C-layout -> out[bh][q][d], float4 along d
#pragma unroll
  for (int dr = 0; dr < 4; ++dr) {
    float4 o;
    o.x = acc[dr][0]; o.y = acc[dr][1];
    o.z = acc[dr][2]; o.w = acc[dr][3];
    *(float4*)(out + ((size_t)bh * S_LEN + q0 + l15) * DH + 16 * dr + 4 * g) = o;
  }

  // ---------------- PASS B: staged K, stream attention ----------------
  float* att = out + (size_t)4194304 + (size_t)bh * S_LEN * S_LEN;
  for (int t0 = 0; t0 < S_LEN; t0 += 128) {
    __syncthreads();
    {  // stage K tile
      const char* src = ksrc_bh + (size_t)t0 * 128;
#pragma unroll
      for (int it = 0; it < 2; ++it) {
        int idx = it * 512 + tid;
        int r = idx >> 3, c = idx & 7;
        int4 val = *(const int4*)(src + r * 128 + c * 16);
        *(int4*)(kbuf + r * 128 + ((c * 16) ^ ((r & 7) << 4))) = val;
      }
    }
    __syncthreads();

    const int q = q0 + l15;
#pragma unroll
    for (int tc = 0; tc < 8; ++tc) {
      const char* rowp = kbuf + (16 * tc + l15) * 128;
      short8 a0 = *(const short8*)(rowp + ((16 * g) ^ sw));
      short8 a1 = *(const short8*)(rowp + ((64 + 16 * g) ^ sw));
      f32x4 z = (f32x4){0.f, 0.f, 0.f, 0.f};
      f32x4 t0f = __builtin_amdgcn_mfma_f32_16x16x32_bf16(a0, qf[0], z, 0, 0, 0);
      f32x4 sff = __builtin_amdgcn_mfma_f32_16x16x32_bf16(a1, qf[1], t0f, 0, 0, 0);
      const int t = t0 + 16 * tc + 4 * g;
      size_t eidx = (size_t)q * S_LEN + t;
      int m0, m1, m2, m3;
      if (stride == 1) {
        unsigned mv = *(const unsigned*)(mb + eidx);
        m0 = mv & 0xff; m1 = (mv >> 8) & 0xff; m2 = (mv >> 16) & 0xff; m3 = (mv >> 24) & 0xff;
      } else {
        uint4 mv = *(const uint4*)(mb + eidx * 4);
        m0 = mv.x; m1 = mv.y; m2 = mv.z; m3 = mv.w;
      }
      float s0 = m0 ? -1e9f : sff[0] * 0.125f;
      float s1 = m1 ? -1e9f : sff[1] * 0.125f;
      float s2 = m2 ? -1e9f : sff[2] * 0.125f;
      float s3 = m3 ? -1e9f : sff[3] * 0.125f;
      float4 e;
      e.x = __expf(s0) * inv;
      e.y = __expf(s1) * inv;
      e.z = __expf(s2) * inv;
      e.w = __expf(s3) * inv;
      *(float4*)(att + eidx) = e;
    }
  }
}

extern "C" void kernel_launch(void* const* d_in, const int* in_sizes, int n_in,
                              void* d_out, int out_size, void* d_ws, size_t ws_size,
                              hipStream_t stream) {
  (void)in_sizes; (void)n_in; (void)out_size; (void)ws_size;
  const float* q = (const float*)d_in[0];
  const float* k = (const float*)d_in[1];
  const float* v = (const float*)d_in[2];
  const unsigned char* mask = (const unsigned char*)d_in[3];
  float* out = (float*)d_out;

  char* ws = (char*)d_ws;
  int* flag = (int*)ws;
  char* kbf = ws + 256;                           // 8 MiB bf16 K
  char* vtbf = ws + 256 + 8 * 1024 * 1024;        // 8 MiB bf16 V^T

  detect_stride_k<<<1, 256, 0, stream>>>(mask, flag);
  conv_k_kernel<<<2048, 256, 0, stream>>>(k, kbf);
  trans_v_kernel<<<4096, 256, 0, stream>>>(v, vtbf);
  attn_fused<<<512, 512, 0, stream>>>(q, mask, kbf, vtbf, flag, out);
}

// Round 8
// 347.205 us; speedup vs baseline: 1.6490x; 1.0094x over previous
//
#include <hip/hip_runtime.h>

typedef __attribute__((ext_vector_type(8))) short short8;
typedef __attribute__((ext_vector_type(4))) float f32x4;

#define S_LEN 2048
#define DH 64

__device__ __forceinline__ unsigned short f2bf(float x) {
  unsigned u = __builtin_bit_cast(unsigned, x);
  u += 0x7fffu + ((u >> 16) & 1u);
  return (unsigned short)(u >> 16);
}

// ---- detect whether mask was passed as uint8 (stride 1) or int32 (stride 4)
__global__ void detect_stride_k(const unsigned char* __restrict__ m, int* flag) {
  __shared__ int any;
  if (threadIdx.x == 0) any = 0;
  __syncthreads();
  int acc = 0;
  for (int i = threadIdx.x; i < 4096; i += 256)
    if (i & 3) acc |= m[i];
  if (acc) atomicOr(&any, 1);
  __syncthreads();
  if (threadIdx.x == 0) *flag = any ? 1 : 4;
}

// ---- K: f32 -> bf16, row-major [bh][t][d]
__global__ void conv_k_kernel(const float* __restrict__ k, char* __restrict__ kbf) {
  int idx = blockIdx.x * 256 + threadIdx.x;  // 524288 threads, 8 elems each
  const float4* s = (const float4*)k + (size_t)idx * 2;
  float4 a = s[0], b = s[1];
  int4 o;
  o.x = (int)f2bf(a.x) | ((int)f2bf(a.y) << 16);
  o.y = (int)f2bf(a.z) | ((int)f2bf(a.w) << 16);
  o.z = (int)f2bf(b.x) | ((int)f2bf(b.y) << 16);
  o.w = (int)f2bf(b.z) | ((int)f2bf(b.w) << 16);
  ((int4*)kbf)[idx] = o;
}

// ---- V: f32 [bh][t][d] -> bf16 transposed [bh][d][t]
__global__ void trans_v_kernel(const float* __restrict__ v, char* __restrict__ vtbf) {
  int gt = blockIdx.x * 256 + threadIdx.x;
  int wid = gt >> 6;            // 16384 wave-jobs
  int lane = gt & 63;
  int bh = wid >> 9;
  int rem = wid & 511;
  int d0 = (rem >> 5) * 4;      // 0,4,...,60
  int t = (rem & 31) * 64 + lane;
  float4 val = *(const float4*)(v + ((size_t)bh * S_LEN + t) * DH + d0);
  unsigned short* o = (unsigned short*)vtbf;
  size_t base = ((size_t)bh * DH + d0) * S_LEN + t;
  o[base]             = f2bf(val.x);
  o[base + S_LEN]     = f2bf(val.y);
  o[base + 2 * S_LEN] = f2bf(val.z);
  o[base + 3 * S_LEN] = f2bf(val.w);
}

// ======= FUSED: double-buffered async staging (global_load_lds) =============
// 512 blocks x 8 waves (16 q-rows each); 2 blocks/CU; 1 barrier per tile.
__global__ __launch_bounds__(512, 4)
void attn_fused(const float* __restrict__ qsrc,
                const unsigned char* __restrict__ maskb,
                const char* __restrict__ kbf,
                const char* __restrict__ vtbf,
                const int* __restrict__ flagp,
                float* __restrict__ out) {
  // 80 KiB: kbuf[2][16K] | vbuf[2][16K] | pbuf[16K]
  __shared__ __align__(16) char smem[81920];

  const int tid = threadIdx.x;
  const int lane = tid & 63;
  const int w = tid >> 6;              // 0..7
  const int l15 = lane & 15;
  const int g = lane >> 4;
  const int sw = (l15 & 7) << 4;

  // XCD-aware swizzle: 512 blocks -> 4 consecutive bh per XCD
  int raw = blockIdx.x;
  int swz = (raw & 7) * 64 + (raw >> 3);
  const int bh = swz >> 4;
  const int qblk = swz & 15;
  const int b = bh >> 4;
  const int q0 = qblk * 128 + w * 16;  // this wave's 16 q-rows

  const int stride = *flagp;
  const unsigned char* mb = maskb + (size_t)b * S_LEN * S_LEN * (size_t)stride;
  const char* ksrc_bh = kbf + (size_t)bh * (S_LEN * DH * 2);
  const char* vsrc_bh = vtbf + (size_t)bh * (DH * S_LEN * 2);
  char* pb = smem + 65536 + w * 2048;  // 16 rows x 128 B, wave-private

  // per-wave async stage of 1/8 of a K tile (2 KB): linear LDS dest,
  // inverse-swizzled global source (rule #21)
  auto stageK = [&](int buf, int t0) {
    char* dst = smem + buf * 16384;
#pragma unroll
    for (int it = 0; it < 2; ++it) {
      int o = (w * 2 + it) * 1024 + lane * 16;
      int r = o >> 7;
      int inner = o & 127;
      const char* gp = ksrc_bh + (size_t)t0 * 128 + r * 128 + (inner ^ ((r & 7) << 4));
      __builtin_amdgcn_global_load_lds((const unsigned*)gp,
                                       (unsigned*)(dst + (w * 2 + it) * 1024), 16, 0, 0);
    }
  };
  auto stageV = [&](int buf, int t0) {
    char* dst = smem + 32768 + buf * 16384;
#pragma unroll
    for (int it = 0; it < 2; ++it) {
      int o = (w * 2 + it) * 1024 + lane * 16;
      int r = o >> 8;
      int inner = o & 255;
      const char* gp = vsrc_bh + (size_t)t0 * 2 + (size_t)r * (S_LEN * 2) +
                       (inner ^ ((r & 7) << 4));
      __builtin_amdgcn_global_load_lds((const unsigned*)gp,
                                       (unsigned*)(dst + (w * 2 + it) * 1024), 16, 0, 0);
    }
  };

  // Q fragments (B operand of swapped QK^T): lane holds Q[q0+l15][32kc+8g+j]
  short8 qf[2];
#pragma unroll
  for (int kc = 0; kc < 2; ++kc) {
    const float* qp = qsrc + ((size_t)bh * S_LEN + q0 + l15) * DH + 32 * kc + 8 * g;
    float4 x = *(const float4*)qp;
    float4 y = *(const float4*)(qp + 4);
    short8 f;
    f[0] = (short)f2bf(x.x); f[1] = (short)f2bf(x.y);
    f[2] = (short)f2bf(x.z); f[3] = (short)f2bf(x.w);
    f[4] = (short)f2bf(y.x); f[5] = (short)f2bf(y.y);
    f[6] = (short)f2bf(y.z); f[7] = (short)f2bf(y.w);
    qf[kc] = f;
  }

  f32x4 acc[4];
#pragma unroll
  for (int i = 0; i < 4; ++i) acc[i] = (f32x4){0.f, 0.f, 0.f, 0.f};
  float lp = 0.f;

  // ---------------- PASS A (pipelined) ----------------
  stageK(0, 0);
  stageV(0, 0);
  __syncthreads();
  int cur = 0;

  for (int t0 = 0; t0 < S_LEN; t0 += 128) {
    if (t0 + 128 < S_LEN) {            // async prefetch of next tile
      stageK(cur ^ 1, t0 + 128);
      stageV(cur ^ 1, t0 + 128);
    }
    const char* kbuf = smem + cur * 16384;
    const char* vbuf = smem + 32768 + cur * 16384;

    // GEMM1 (swapped): lane holds S[q=q0+l15][t=t0+16tc+4g+r]
    f32x4 sf[8];
#pragma unroll
    for (int tc = 0; tc < 8; ++tc) {
      const char* rowp = kbuf + (16 * tc + l15) * 128;
      short8 a0 = *(const short8*)(rowp + ((16 * g) ^ sw));
      short8 a1 = *(const short8*)(rowp + ((64 + 16 * g) ^ sw));
      f32x4 z = (f32x4){0.f, 0.f, 0.f, 0.f};
      f32x4 t00 = __builtin_amdgcn_mfma_f32_16x16x32_bf16(a0, qf[0], z, 0, 0, 0);
      sf[tc] = __builtin_amdgcn_mfma_f32_16x16x32_bf16(a1, qf[1], t00, 0, 0, 0);
    }

    // two 64-t halves: mask+exp+pack P -> GEMM2 (wave-private pbuf, no barrier)
    const int q = q0 + l15;
#pragma unroll
    for (int h = 0; h < 2; ++h) {
      char* pbr = pb + l15 * 128;
#pragma unroll
      for (int tq = 0; tq < 4; ++tq) {
        const int tc = 4 * h + tq;
        const int t = t0 + 16 * tc + 4 * g;
        size_t eidx = (size_t)q * S_LEN + t;
        int m0, m1, m2, m3;
        if (stride == 1) {
          unsigned mv = *(const unsigned*)(mb + eidx);
          m0 = mv & 0xff; m1 = (mv >> 8) & 0xff; m2 = (mv >> 16) & 0xff; m3 = (mv >> 24) & 0xff;
        } else {
          uint4 mv = *(const uint4*)(mb + eidx * 4);
          m0 = mv.x; m1 = mv.y; m2 = mv.z; m3 = mv.w;
        }
        float s0 = m0 ? -1e9f : sf[tc][0] * 0.125f;
        float s1 = m1 ? -1e9f : sf[tc][1] * 0.125f;
        float s2 = m2 ? -1e9f : sf[tc][2] * 0.125f;
        float s3 = m3 ? -1e9f : sf[tc][3] * 0.125f;
        lp += __expf(s0) + __expf(s1) + __expf(s2) + __expf(s3);
        int2 pk;
        pk.x = (int)f2bf(s0) | ((int)f2bf(s1) << 16);
        pk.y = (int)f2bf(s2) | ((int)f2bf(s3) << 16);
        *(int2*)(pbr + ((32 * tq + 8 * g) ^ sw)) = pk;
      }
      short8 p0 = *(const short8*)(pb + l15 * 128 + ((16 * g) ^ sw));
      short8 p1 = *(const short8*)(pb + l15 * 128 + ((64 + 16 * g) ^ sw));
#pragma unroll
      for (int dr = 0; dr < 4; ++dr) {
        const char* vr = vbuf + (16 * dr + l15) * 256;
        short8 v0 = *(const short8*)(vr + ((h * 128 + 16 * g) ^ sw));
        short8 v1 = *(const short8*)(vr + ((h * 128 + 64 + 16 * g) ^ sw));
        acc[dr] = __builtin_amdgcn_mfma_f32_16x16x32_bf16(v0, p0, acc[dr], 0, 0, 0);
        acc[dr] = __builtin_amdgcn_mfma_f32_16x16x32_bf16(v1, p1, acc[dr], 0, 0, 0);
      }
    }

    __syncthreads();   // drains prefetch (covered by compute) + guards buffers
    cur ^= 1;
  }

  // row sums (row q0+l15 lives on lanes {l15, +16, +32, +48})
  float l = lp;
  l += __shfl_xor(l, 16);
  l += __shfl_xor(l, 32);
  const float inv = 1.0f / l;

  // write results: acc^T C-layout -> out[bh][q][d], float4 along d
#pragma unroll
  for (int dr = 0; dr < 4; ++dr) {
    float4 o;
    o.x = acc[dr][0]; o.y = acc[dr][1];
    o.z = acc[dr][2]; o.w = acc[dr][3];
    *(float4*)(out + ((size_t)bh * S_LEN + q0 + l15) * DH + 16 * dr + 4 * g) = o;
  }

  // ---------------- PASS B (pipelined K staging) ----------------
  float* att = out + (size_t)4194304 + (size_t)bh * S_LEN * S_LEN;
  stageK(0, 0);
  __syncthreads();
  cur = 0;

  for (int t0 = 0; t0 < S_LEN; t0 += 128) {
    if (t0 + 128 < S_LEN) stageK(cur ^ 1, t0 + 128);
    const char* kbuf = smem + cur * 16384;

    const int q = q0 + l15;
#pragma unroll
    for (int tc = 0; tc < 8; ++tc) {
      const char* rowp = kbuf + (16 * tc + l15) * 128;
      short8 a0 = *(const short8*)(rowp + ((16 * g) ^ sw));
      short8 a1 = *(const short8*)(rowp + ((64 + 16 * g) ^ sw));
      f32x4 z = (f32x4){0.f, 0.f, 0.f, 0.f};
      f32x4 t0f = __builtin_amdgcn_mfma_f32_16x16x32_bf16(a0, qf[0], z, 0, 0, 0);
      f32x4 sff = __builtin_amdgcn_mfma_f32_16x16x32_bf16(a1, qf[1], t0f, 0, 0, 0);
      const int t = t0 + 16 * tc + 4 * g;
      size_t eidx = (size_t)q * S_LEN + t;
      int m0, m1, m2, m3;
      if (stride == 1) {
        unsigned mv = *(const unsigned*)(mb + eidx);
        m0 = mv & 0xff; m1 = (mv >> 8) & 0xff; m2 = (mv >> 16) & 0xff; m3 = (mv >> 24) & 0xff;
      } else {
        uint4 mv = *(const uint4*)(mb + eidx * 4);
        m0 = mv.x; m1 = mv.y; m2 = mv.z; m3 = mv.w;
      }
      float s0 = m0 ? -1e9f : sff[0] * 0.125f;
      float s1 = m1 ? -1e9f : sff[1] * 0.125f;
      float s2 = m2 ? -1e9f : sff[2] * 0.125f;
      float s3 = m3 ? -1e9f : sff[3] * 0.125f;
      float4 e;
      e.x = __expf(s0) * inv;
      e.y = __expf(s1) * inv;
      e.z = __expf(s2) * inv;
      e.w = __expf(s3) * inv;
      *(float4*)(att + eidx) = e;
    }

    __syncthreads();
    cur ^= 1;
  }
}

extern "C" void kernel_launch(void* const* d_in, const int* in_sizes, int n_in,
                              void* d_out, int out_size, void* d_ws, size_t ws_size,
                              hipStream_t stream) {
  (void)in_sizes; (void)n_in; (void)out_size; (void)ws_size;
  const float* q = (const float*)d_in[0];
  const float* k = (const float*)d_in[1];
  const float* v = (const float*)d_in[2];
  const unsigned char* mask = (const unsigned char*)d_in[3];
  float* out = (float*)d_out;

  char* ws = (char*)d_ws;
  int* flag = (int*)ws;
  char* kbf = ws + 256;                           // 8 MiB bf16 K
  char* vtbf = ws + 256 + 8 * 1024 * 1024;        // 8 MiB bf16 V^T

  detect_stride_k<<<1, 256, 0, stream>>>(mask, flag);
  conv_k_kernel<<<2048, 256, 0, stream>>>(k, kbf);
  trans_v_kernel<<<4096, 256, 0, stream>>>(v, vtbf);
  attn_fused<<<512, 512, 0, stream>>>(q, mask, kbf, vtbf, flag, out);
}

// Round 9
// 217.305 us; speedup vs baseline: 2.6348x; 1.5978x over previous
//
#include <hip/hip_runtime.h>

typedef __attribute__((ext_vector_type(8))) short short8;
typedef __attribute__((ext_vector_type(4))) float f32x4;

#define S_LEN 2048
#define DH 64

__device__ __forceinline__ unsigned short f2bf(float x) {
  unsigned u = __builtin_bit_cast(unsigned, x);
  u += 0x7fffu + ((u >> 16) & 1u);
  return (unsigned short)(u >> 16);
}

// ---- detect whether mask was passed as uint8 (stride 1) or int32 (stride 4)
__global__ void detect_stride_k(const unsigned char* __restrict__ m, int* flag) {
  __shared__ int any;
  if (threadIdx.x == 0) any = 0;
  __syncthreads();
  int acc = 0;
  for (int i = threadIdx.x; i < 4096; i += 256)
    if (i & 3) acc |= m[i];
  if (acc) atomicOr(&any, 1);
  __syncthreads();
  if (threadIdx.x == 0) *flag = any ? 1 : 4;
}

// ---- pack mask to 1 bit per position: bits[b][q][t/32] (2 MB total, L2-warm)
__global__ void pack_mask_k(const unsigned char* __restrict__ m,
                            const int* __restrict__ flagp,
                            unsigned* __restrict__ bits) {
  int idx = blockIdx.x * 256 + threadIdx.x;   // 262144 words, 32 positions each
  unsigned w = 0;
  if (*flagp == 1) {
    const uint4* p = (const uint4*)(m + (size_t)idx * 32);
    uint4 a = p[0], bq = p[1];
    unsigned arr[8] = {a.x, a.y, a.z, a.w, bq.x, bq.y, bq.z, bq.w};
#pragma unroll
    for (int d = 0; d < 8; ++d)
#pragma unroll
      for (int j = 0; j < 4; ++j)
        w |= (((arr[d] >> (8 * j)) & 255u) != 0u ? 1u : 0u) << (d * 4 + j);
  } else {
    const uint4* p = (const uint4*)m + (size_t)idx * 8;
#pragma unroll
    for (int d = 0; d < 8; ++d) {
      uint4 v = p[d];
      w |= (v.x ? 1u : 0u) << (d * 4);
      w |= (v.y ? 1u : 0u) << (d * 4 + 1);
      w |= (v.z ? 1u : 0u) << (d * 4 + 2);
      w |= (v.w ? 1u : 0u) << (d * 4 + 3);
    }
  }
  bits[idx] = w;
}

// ---- K: f32 -> bf16, row-major [bh][t][d]
__global__ void conv_k_kernel(const float* __restrict__ k, char* __restrict__ kbf) {
  int idx = blockIdx.x * 256 + threadIdx.x;  // 524288 threads, 8 elems each
  const float4* s = (const float4*)k + (size_t)idx * 2;
  float4 a = s[0], b = s[1];
  int4 o;
  o.x = (int)f2bf(a.x) | ((int)f2bf(a.y) << 16);
  o.y = (int)f2bf(a.z) | ((int)f2bf(a.w) << 16);
  o.z = (int)f2bf(b.x) | ((int)f2bf(b.y) << 16);
  o.w = (int)f2bf(b.z) | ((int)f2bf(b.w) << 16);
  ((int4*)kbf)[idx] = o;
}

// ---- V: f32 [bh][t][d] -> bf16 transposed [bh][d][t]
__global__ void trans_v_kernel(const float* __restrict__ v, char* __restrict__ vtbf) {
  int gt = blockIdx.x * 256 + threadIdx.x;
  int wid = gt >> 6;            // 16384 wave-jobs
  int lane = gt & 63;
  int bh = wid >> 9;
  int rem = wid & 511;
  int d0 = (rem >> 5) * 4;      // 0,4,...,60
  int t = (rem & 31) * 64 + lane;
  float4 val = *(const float4*)(v + ((size_t)bh * S_LEN + t) * DH + d0);
  unsigned short* o = (unsigned short*)vtbf;
  size_t base = ((size_t)bh * DH + d0) * S_LEN + t;
  o[base]             = f2bf(val.x);
  o[base + S_LEN]     = f2bf(val.y);
  o[base + 2 * S_LEN] = f2bf(val.z);
  o[base + 3 * S_LEN] = f2bf(val.w);
}

// ======= FUSED: dbuf async staging + bitmask (prefetched, L2-resident) ======
// 512 blocks x 8 waves (16 q-rows each); 2 blocks/CU; 1 barrier per tile.
__global__ __launch_bounds__(512, 4)
void attn_fused(const float* __restrict__ qsrc,
                const unsigned* __restrict__ mbits,
                const char* __restrict__ kbf,
                const char* __restrict__ vtbf,
                float* __restrict__ out) {
  // 80 KiB: kbuf[2][16K] | vbuf[2][16K] | pbuf[16K]
  __shared__ __align__(16) char smem[81920];

  const int tid = threadIdx.x;
  const int lane = tid & 63;
  const int w = tid >> 6;              // 0..7
  const int l15 = lane & 15;
  const int g = lane >> 4;
  const int sw = (l15 & 7) << 4;

  // XCD-aware swizzle: 512 blocks -> 4 consecutive bh per XCD
  int raw = blockIdx.x;
  int swz = (raw & 7) * 64 + (raw >> 3);
  const int bh = swz >> 4;
  const int qblk = swz & 15;
  const int b = bh >> 4;
  const int q0 = qblk * 128 + w * 16;  // this wave's 16 q-rows

  const char* ksrc_bh = kbf + (size_t)bh * (S_LEN * DH * 2);
  const char* vsrc_bh = vtbf + (size_t)bh * (DH * S_LEN * 2);
  char* pb = smem + 65536 + w * 2048;  // 16 rows x 128 B, wave-private

  // this lane's q-row bitmask pointer: 64 words per row
  const unsigned* mrow = mbits + (size_t)b * (S_LEN * (S_LEN / 32)) +
                         (size_t)(q0 + l15) * (S_LEN / 32);

  // per-wave async stage of 1/8 of a K tile (2 KB): linear LDS dest,
  // inverse-swizzled global source (rule #21)
  auto stageK = [&](int buf, int t0) {
    char* dst = smem + buf * 16384;
#pragma unroll
    for (int it = 0; it < 2; ++it) {
      int o = (w * 2 + it) * 1024 + lane * 16;
      int r = o >> 7;
      int inner = o & 127;
      const char* gp = ksrc_bh + (size_t)t0 * 128 + r * 128 + (inner ^ ((r & 7) << 4));
      __builtin_amdgcn_global_load_lds((const unsigned*)gp,
                                       (unsigned*)(dst + (w * 2 + it) * 1024), 16, 0, 0);
    }
  };
  auto stageV = [&](int buf, int t0) {
    char* dst = smem + 32768 + buf * 16384;
#pragma unroll
    for (int it = 0; it < 2; ++it) {
      int o = (w * 2 + it) * 1024 + lane * 16;
      int r = o >> 8;
      int inner = o & 255;
      const char* gp = vsrc_bh + (size_t)t0 * 2 + (size_t)r * (S_LEN * 2) +
                       (inner ^ ((r & 7) << 4));
      __builtin_amdgcn_global_load_lds((const unsigned*)gp,
                                       (unsigned*)(dst + (w * 2 + it) * 1024), 16, 0, 0);
    }
  };

  // Q fragments (B operand of swapped QK^T): lane holds Q[q0+l15][32kc+8g+j]
  short8 qf[2];
#pragma unroll
  for (int kc = 0; kc < 2; ++kc) {
    const float* qp = qsrc + ((size_t)bh * S_LEN + q0 + l15) * DH + 32 * kc + 8 * g;
    float4 x = *(const float4*)qp;
    float4 y = *(const float4*)(qp + 4);
    short8 f;
    f[0] = (short)f2bf(x.x); f[1] = (short)f2bf(x.y);
    f[2] = (short)f2bf(x.z); f[3] = (short)f2bf(x.w);
    f[4] = (short)f2bf(y.x); f[5] = (short)f2bf(y.y);
    f[6] = (short)f2bf(y.z); f[7] = (short)f2bf(y.w);
    qf[kc] = f;
  }

  f32x4 acc[4];
#pragma unroll
  for (int i = 0; i < 4; ++i) acc[i] = (f32x4){0.f, 0.f, 0.f, 0.f};
  float lp = 0.f;

  // ---------------- PASS A (pipelined) ----------------
  stageK(0, 0);
  stageV(0, 0);
  uint4 mw = *(const uint4*)mrow;      // tile-0 mask bits (128 t = 16 B)
  __syncthreads();
  int cur = 0;

  for (int t0 = 0; t0 < S_LEN; t0 += 128) {
    uint4 mw_n;
    if (t0 + 128 < S_LEN) {            // async prefetch of next tile
      stageK(cur ^ 1, t0 + 128);
      stageV(cur ^ 1, t0 + 128);
      mw_n = *(const uint4*)(mrow + (t0 + 128) / 32);
    }
    const char* kbuf = smem + cur * 16384;
    const char* vbuf = smem + 32768 + cur * 16384;

    // GEMM1 (swapped): lane holds S[q=q0+l15][t=t0+16tc+4g+r]
    f32x4 sf[8];
#pragma unroll
    for (int tc = 0; tc < 8; ++tc) {
      const char* rowp = kbuf + (16 * tc + l15) * 128;
      short8 a0 = *(const short8*)(rowp + ((16 * g) ^ sw));
      short8 a1 = *(const short8*)(rowp + ((64 + 16 * g) ^ sw));
      f32x4 z = (f32x4){0.f, 0.f, 0.f, 0.f};
      f32x4 t00 = __builtin_amdgcn_mfma_f32_16x16x32_bf16(a0, qf[0], z, 0, 0, 0);
      sf[tc] = __builtin_amdgcn_mfma_f32_16x16x32_bf16(a1, qf[1], t00, 0, 0, 0);
    }

    // two 64-t halves: mask+exp+pack P -> GEMM2 (wave-private pbuf, no barrier)
    const unsigned mwa[4] = {mw.x, mw.y, mw.z, mw.w};
#pragma unroll
    for (int h = 0; h < 2; ++h) {
      char* pbr = pb + l15 * 128;
#pragma unroll
      for (int tq = 0; tq < 4; ++tq) {
        const int tc = 4 * h + tq;
        // 4 mask bits for t = t0+16tc+4g+(0..3)
        unsigned nib = (mwa[tc >> 1] >> (16 * (tc & 1) + 4 * g)) & 15u;
        float s0 = (nib & 1u) ? -1e9f : sf[tc][0] * 0.125f;
        float s1 = (nib & 2u) ? -1e9f : sf[tc][1] * 0.125f;
        float s2 = (nib & 4u) ? -1e9f : sf[tc][2] * 0.125f;
        float s3 = (nib & 8u) ? -1e9f : sf[tc][3] * 0.125f;
        lp += __expf(s0) + __expf(s1) + __expf(s2) + __expf(s3);
        int2 pk;
        pk.x = (int)f2bf(s0) | ((int)f2bf(s1) << 16);
        pk.y = (int)f2bf(s2) | ((int)f2bf(s3) << 16);
        *(int2*)(pbr + ((32 * tq + 8 * g) ^ sw)) = pk;
      }
      short8 p0 = *(const short8*)(pb + l15 * 128 + ((16 * g) ^ sw));
      short8 p1 = *(const short8*)(pb + l15 * 128 + ((64 + 16 * g) ^ sw));
#pragma unroll
      for (int dr = 0; dr < 4; ++dr) {
        const char* vr = vbuf + (16 * dr + l15) * 256;
        short8 v0 = *(const short8*)(vr + ((h * 128 + 16 * g) ^ sw));
        short8 v1 = *(const short8*)(vr + ((h * 128 + 64 + 16 * g) ^ sw));
        acc[dr] = __builtin_amdgcn_mfma_f32_16x16x32_bf16(v0, p0, acc[dr], 0, 0, 0);
        acc[dr] = __builtin_amdgcn_mfma_f32_16x16x32_bf16(v1, p1, acc[dr], 0, 0, 0);
      }
    }

    mw = mw_n;
    __syncthreads();   // drains prefetch (covered by compute) + guards buffers
    cur ^= 1;
  }

  // row sums (row q0+l15 lives on lanes {l15, +16, +32, +48})
  float l = lp;
  l += __shfl_xor(l, 16);
  l += __shfl_xor(l, 32);
  const float inv = 1.0f / l;

  // write results: acc^T C-layout -> out[bh][q][d], float4 along d
#pragma unroll
  for (int dr = 0; dr < 4; ++dr) {
    float4 o;
    o.x = acc[dr][0]; o.y = acc[dr][1];
    o.z = acc[dr][2]; o.w = acc[dr][3];
    *(float4*)(out + ((size_t)bh * S_LEN + q0 + l15) * DH + 16 * dr + 4 * g) = o;
  }

  // ---------------- PASS B (pipelined K staging) ----------------
  float* att = out + (size_t)4194304 + (size_t)bh * S_LEN * S_LEN;
  stageK(0, 0);
  mw = *(const uint4*)mrow;
  __syncthreads();
  cur = 0;

  for (int t0 = 0; t0 < S_LEN; t0 += 128) {
    uint4 mw_n;
    if (t0 + 128 < S_LEN) {
      stageK(cur ^ 1, t0 + 128);
      mw_n = *(const uint4*)(mrow + (t0 + 128) / 32);
    }
    const char* kbuf = smem + cur * 16384;

    const int q = q0 + l15;
    const unsigned mwa[4] = {mw.x, mw.y, mw.z, mw.w};
#pragma unroll
    for (int tc = 0; tc < 8; ++tc) {
      const char* rowp = kbuf + (16 * tc + l15) * 128;
      short8 a0 = *(const short8*)(rowp + ((16 * g) ^ sw));
      short8 a1 = *(const short8*)(rowp + ((64 + 16 * g) ^ sw));
      f32x4 z = (f32x4){0.f, 0.f, 0.f, 0.f};
      f32x4 t0f = __builtin_amdgcn_mfma_f32_16x16x32_bf16(a0, qf[0], z, 0, 0, 0);
      f32x4 sff = __builtin_amdgcn_mfma_f32_16x16x32_bf16(a1, qf[1], t0f, 0, 0, 0);
      const int t = t0 + 16 * tc + 4 * g;
      size_t eidx = (size_t)q * S_LEN + t;
      unsigned nib = (mwa[tc >> 1] >> (16 * (tc & 1) + 4 * g)) & 15u;
      float s0 = (nib & 1u) ? -1e9f : sff[0] * 0.125f;
      float s1 = (nib & 2u) ? -1e9f : sff[1] * 0.125f;
      float s2 = (nib & 4u) ? -1e9f : sff[2] * 0.125f;
      float s3 = (nib & 8u) ? -1e9f : sff[3] * 0.125f;
      float4 e;
      e.x = __expf(s0) * inv;
      e.y = __expf(s1) * inv;
      e.z = __expf(s2) * inv;
      e.w = __expf(s3) * inv;
      *(float4*)(att + eidx) = e;
    }

    mw = mw_n;
    __syncthreads();
    cur ^= 1;
  }
}

extern "C" void kernel_launch(void* const* d_in, const int* in_sizes, int n_in,
                              void* d_out, int out_size, void* d_ws, size_t ws_size,
                              hipStream_t stream) {
  (void)in_sizes; (void)n_in; (void)out_size; (void)ws_size;
  const float* q = (const float*)d_in[0];
  const float* k = (const float*)d_in[1];
  const float* v = (const float*)d_in[2];
  const unsigned char* mask = (const unsigned char*)d_in[3];
  float* out = (float*)d_out;

  char* ws = (char*)d_ws;
  int* flag = (int*)ws;
  char* kbf = ws + 256;                           // 8 MiB bf16 K
  char* vtbf = ws + 256 + 8 * 1024 * 1024;        // 8 MiB bf16 V^T
  unsigned* bits = (unsigned*)(ws + 256 + 16 * 1024 * 1024);  // 1 MiB bitmask

  detect_stride_k<<<1, 256, 0, stream>>>(mask, flag);
  pack_mask_k<<<1024, 256, 0, stream>>>(mask, flag, bits);
  conv_k_kernel<<<2048, 256, 0, stream>>>(k, kbf);
  trans_v_kernel<<<4096, 256, 0, stream>>>(v, vtbf);
  attn_fused<<<512, 512, 0, stream>>>(q, bits, kbf, vtbf, out);
}